// Round 1
// baseline (1950.668 us; speedup 1.0000x reference)
//
#include <hip/hip_runtime.h>
#include <hip/hip_bf16.h>

typedef unsigned short u16;
typedef unsigned int u32;
typedef float f32x4 __attribute__((ext_vector_type(4)));
typedef __bf16 bf16x8 __attribute__((ext_vector_type(8)));

#define NB 2
#define NT 1024
#define ND 1024
#define NH 16
#define HDIM 64
#define NL 6
#define NV 32000
#define ND4 4096
#define BT (NB * NT)
#define L2E 1.44269504f

__device__ __forceinline__ u16 f2b(float f) {
  u32 u = __builtin_bit_cast(u32, f);
  u32 r = (u + 0x7FFFu + ((u >> 16) & 1u)) >> 16;
  return (u16)r;
}

__device__ __forceinline__ void gl_lds16(const void* g, void* lds) {
  __builtin_amdgcn_global_load_lds((const __attribute__((address_space(1))) u32*)g,
                                   (__attribute__((address_space(3))) u32*)lds, 16, 0, 0);
}

// ---------------------------------------------------------------- embedding
__global__ void k_embed(const int* __restrict__ idx, const float* __restrict__ tok,
                        const float* __restrict__ pos, float* __restrict__ xf,
                        u16* __restrict__ xb) {
  int row = blockIdx.x;
  int t = row & (NT - 1);
  int tk = idx[row];
  int c = threadIdx.x * 4;
  float4 a = *(const float4*)(tok + (size_t)tk * ND + c);
  float4 p = *(const float4*)(pos + (size_t)t * ND + c);
  float4 s = make_float4(a.x + p.x, a.y + p.y, a.z + p.z, a.w + p.w);
  *(float4*)(xf + (size_t)row * ND + c) = s;
  u16* o = xb + (size_t)row * ND + c;
  *(u32*)(o + 0) = (u32)f2b(s.x) | ((u32)f2b(s.y) << 16);
  *(u32*)(o + 2) = (u32)f2b(s.z) | ((u32)f2b(s.w) << 16);
}

// --------------------------------------------- f32 [K][N] -> bf16 [N][K] transpose
__device__ __forceinline__ void tr_tile(const float* in, int in_rs, u16* out, int out_rs,
                                        int k0, int n0, float (*t)[65]) {
  int tid = threadIdx.x;
#pragma unroll
  for (int i = 0; i < 16; ++i) {
    int e = tid + 256 * i;
    int r = e >> 6, c = e & 63;
    t[r][c] = in[(size_t)(k0 + r) * in_rs + n0 + c];
  }
  __syncthreads();
#pragma unroll
  for (int i = 0; i < 16; ++i) {
    int e = tid + 256 * i;
    int r = e >> 6, c = e & 63;
    out[(size_t)(n0 + r) * out_rs + k0 + c] = f2b(t[c][r]);
  }
}

__global__ void k_transpose(const float* __restrict__ in, u16* __restrict__ out,
                            int K, int N) {
  __shared__ float t[64][65];
  tr_tile(in, N, out, K, blockIdx.y * 64, blockIdx.x * 64, t);
}

// Wq/Wk/Wv [L][H][D][HD] -> packed bf16 [3D][D] (row n = s*1024 + h*64 + e, col k)
__global__ void k_transpose_qkv(const float* __restrict__ Wq, const float* __restrict__ Wk,
                                const float* __restrict__ Wv, u16* __restrict__ out, int l) {
  __shared__ float t[64][65];
  int z = blockIdx.y;
  int s = z >> 4, h = z & 15;
  const float* in = (s == 0 ? Wq : s == 1 ? Wk : Wv) + ((size_t)(l * NH + h)) * ND * HDIM;
  u16* o = out + ((size_t)(s * ND + h * HDIM)) * ND;
  tr_tile(in, HDIM, o, ND, blockIdx.x * 64, 0, t);
}

// ---------------------------------------------------------------- GEMM 128x128, BK=64
// A: bf16 [M][K] row-major; Bt: bf16 [N][K] row-major (pre-transposed weights).
// EPI 0: bf16 store. 1: +bias, f32 store. 2: +bias, relu, bf16. 3: +bias, residual f32+bf16.
template <int EPI>
__global__ void __launch_bounds__(256) k_gemm(const u16* __restrict__ A,
                                              const u16* __restrict__ Bt,
                                              const float* __restrict__ bias,
                                              float* __restrict__ outf,
                                              u16* __restrict__ outb, int K, int N) {
  __shared__ u16 As[128 * 64];
  __shared__ u16 Bs[128 * 64];
  int tid = threadIdx.x;
  int w = tid >> 6, l = tid & 63;
  int l4 = l >> 4, lm = l & 15;
  int wr = w >> 1, wc = w & 1;
  int m0 = blockIdx.y * 128;
  int n0 = blockIdx.x * 128;

  f32x4 acc[4][4];
  f32x4 z = {0.f, 0.f, 0.f, 0.f};
#pragma unroll
  for (int m = 0; m < 4; ++m)
#pragma unroll
    for (int n = 0; n < 4; ++n) acc[m][n] = z;

  const u16* Arow = A + (size_t)m0 * K;
  const u16* Brow = Bt + (size_t)n0 * K;
  int nk = K >> 6;
  for (int kt = 0; kt < nk; ++kt) {
    int k0 = kt * 64;
#pragma unroll
    for (int r = 0; r < 4; ++r) {
      int offw = r * 4096 + w * 1024;      // wave-uniform LDS byte offset
      int offl = offw + l * 16;            // this lane's bytes (for global addr)
      int row = offl >> 7, colb = offl & 127;
      gl_lds16(Arow + (size_t)row * K + k0 + (colb >> 1), (char*)As + offw);
      gl_lds16(Brow + (size_t)row * K + k0 + (colb >> 1), (char*)Bs + offw);
    }
    __syncthreads();  // drains vmcnt before barrier (compiler-emitted)
#pragma unroll
    for (int kk = 0; kk < 2; ++kk) {
      bf16x8 af[4], bfr[4];
#pragma unroll
      for (int m = 0; m < 4; ++m)
        af[m] = *(const bf16x8*)&As[(wr * 64 + m * 16 + lm) * 64 + kk * 32 + l4 * 8];
#pragma unroll
      for (int n = 0; n < 4; ++n)
        bfr[n] = *(const bf16x8*)&Bs[(wc * 64 + n * 16 + lm) * 64 + kk * 32 + l4 * 8];
#pragma unroll
      for (int m = 0; m < 4; ++m)
#pragma unroll
        for (int n = 0; n < 4; ++n)
          acc[m][n] = __builtin_amdgcn_mfma_f32_16x16x32_bf16(af[m], bfr[n], acc[m][n], 0, 0, 0);
    }
    __syncthreads();
  }

#pragma unroll
  for (int m = 0; m < 4; ++m)
#pragma unroll
    for (int n = 0; n < 4; ++n)
#pragma unroll
      for (int j = 0; j < 4; ++j) {
        int row = m0 + wr * 64 + m * 16 + l4 * 4 + j;
        int col = n0 + wc * 64 + n * 16 + lm;
        float v = acc[m][n][j];
        if constexpr (EPI == 0) {
          outb[(size_t)row * N + col] = f2b(v);
        } else if constexpr (EPI == 1) {
          outf[(size_t)row * N + col] = v + bias[col];
        } else if constexpr (EPI == 2) {
          v += bias[col];
          outb[(size_t)row * N + col] = f2b(fmaxf(v, 0.f));
        } else {
          v += bias[col];
          size_t o = (size_t)row * N + col;
          float nx = outf[o] + v;
          outf[o] = nx;
          outb[o] = f2b(nx);
        }
      }
}

// ---------------------------------------------------------------- flash attention
__device__ __forceinline__ float rmax16(float v) {
  v = fmaxf(v, __shfl_xor(v, 1, 64));
  v = fmaxf(v, __shfl_xor(v, 2, 64));
  v = fmaxf(v, __shfl_xor(v, 4, 64));
  v = fmaxf(v, __shfl_xor(v, 8, 64));
  return v;
}
__device__ __forceinline__ float rsum16(float v) {
  v += __shfl_xor(v, 1, 64);
  v += __shfl_xor(v, 2, 64);
  v += __shfl_xor(v, 4, 64);
  v += __shfl_xor(v, 8, 64);
  return v;
}

// grid 256 = (qb:8, h:16, b:2); block 256 (4 waves, 32 q-rows each)
__global__ void __launch_bounds__(256) k_attn(const u16* __restrict__ qkv,
                                              u16* __restrict__ ob) {
  int bid = blockIdx.x;
  int qb = bid & 7, h = (bid >> 3) & 15, b = bid >> 7;
  int tid = threadIdx.x;
  int w = tid >> 6, l = tid & 63;
  int l4 = l >> 4, lm = l & 15;

  __shared__ u16 Ks[128][72];       // K-tile row-major (key pos, e), +8 pad
  __shared__ u16 Vt[64][136];       // V-tile transposed (e, key pos), +8 pad
  __shared__ u16 Pw[4][32][136];    // per-wave P (row, key pos), +8 pad

  const u16* base = qkv + (size_t)b * NT * 3072 + h * HDIM;

  bf16x8 qf[2][2];
#pragma unroll
  for (int m = 0; m < 2; ++m)
#pragma unroll
    for (int kk = 0; kk < 2; ++kk) {
      int tq = qb * 128 + w * 32 + m * 16 + lm;
      qf[m][kk] = *(const bf16x8*)(base + (size_t)tq * 3072 + kk * 32 + l4 * 8);
    }

  f32x4 z = {0.f, 0.f, 0.f, 0.f};
  f32x4 oacc[2][4];
  float mrow[2][4], lrow[2][4];
#pragma unroll
  for (int m = 0; m < 2; ++m) {
#pragma unroll
    for (int n = 0; n < 4; ++n) oacc[m][n] = z;
#pragma unroll
    for (int j = 0; j < 4; ++j) { mrow[m][j] = -1e30f; lrow[m][j] = 0.f; }
  }

  for (int kb = 0; kb <= qb; ++kb) {
    __syncthreads();  // guard prior-iter LDS reads before restaging
#pragma unroll
    for (int i = 0; i < 4; ++i) {
      int c = tid + 256 * i;
      int r = c >> 3, e0 = (c & 7) << 3;
      const u16* src = base + (size_t)(kb * 128 + r) * 3072;
      *(bf16x8*)&Ks[r][e0] = *(const bf16x8*)(src + 1024 + e0);
      union { bf16x8 v; u16 u[8]; } uu;
      uu.v = *(const bf16x8*)(src + 2048 + e0);
#pragma unroll
      for (int j = 0; j < 8; ++j) Vt[e0 + j][r] = uu.u[j];
    }
    __syncthreads();

    // S = Q K^T  (per wave: 32 x 128)
    f32x4 s[2][8];
#pragma unroll
    for (int m = 0; m < 2; ++m)
#pragma unroll
      for (int n = 0; n < 8; ++n) s[m][n] = z;
#pragma unroll
    for (int kk = 0; kk < 2; ++kk)
#pragma unroll
      for (int n = 0; n < 8; ++n) {
        bf16x8 kf = *(const bf16x8*)&Ks[n * 16 + lm][kk * 32 + l4 * 8];
        s[0][n] = __builtin_amdgcn_mfma_f32_16x16x32_bf16(qf[0][kk], kf, s[0][n], 0, 0, 0);
        s[1][n] = __builtin_amdgcn_mfma_f32_16x16x32_bf16(qf[1][kk], kf, s[1][n], 0, 0, 0);
      }

    bool diag = (kb == qb);
#pragma unroll
    for (int m = 0; m < 2; ++m)
#pragma unroll
      for (int j = 0; j < 4; ++j) {
        int rloc = w * 32 + m * 16 + l4 * 4 + j;
        float pv[8];
        float rm = -1e30f;
#pragma unroll
        for (int n = 0; n < 8; ++n) {
          float vv = s[m][n][j] * 0.03125f;  // scale = D^-0.5 = 1/32
          if (diag && (n * 16 + lm > rloc)) vv = -1e30f;
          pv[n] = vv;
          rm = fmaxf(rm, vv);
        }
        rm = rmax16(rm);
        float nm = fmaxf(mrow[m][j], rm);
        float corr = exp2f((mrow[m][j] - nm) * L2E);
        mrow[m][j] = nm;
        float rs = 0.f;
#pragma unroll
        for (int n = 0; n < 8; ++n) {
          float p = exp2f((pv[n] - nm) * L2E);
          pv[n] = p;
          rs += p;
        }
        rs = rsum16(rs);
        lrow[m][j] = lrow[m][j] * corr + rs;
#pragma unroll
        for (int n = 0; n < 4; ++n) oacc[m][n][j] *= corr;
        int prow = m * 16 + l4 * 4 + j;
#pragma unroll
        for (int n = 0; n < 8; ++n) Pw[w][prow][n * 16 + lm] = f2b(pv[n]);
      }
    asm volatile("s_waitcnt lgkmcnt(0)" ::: "memory");  // P writes -> cross-lane reads
    __builtin_amdgcn_sched_barrier(0);

    // O += P V
#pragma unroll
    for (int kk = 0; kk < 4; ++kk) {
      bf16x8 pa0 = *(const bf16x8*)&Pw[w][lm][kk * 32 + l4 * 8];
      bf16x8 pa1 = *(const bf16x8*)&Pw[w][16 + lm][kk * 32 + l4 * 8];
#pragma unroll
      for (int n = 0; n < 4; ++n) {
        bf16x8 vf = *(const bf16x8*)&Vt[n * 16 + lm][kk * 32 + l4 * 8];
        oacc[0][n] = __builtin_amdgcn_mfma_f32_16x16x32_bf16(pa0, vf, oacc[0][n], 0, 0, 0);
        oacc[1][n] = __builtin_amdgcn_mfma_f32_16x16x32_bf16(pa1, vf, oacc[1][n], 0, 0, 0);
      }
    }
  }

#pragma unroll
  for (int m = 0; m < 2; ++m)
#pragma unroll
    for (int n = 0; n < 4; ++n)
#pragma unroll
      for (int j = 0; j < 4; ++j) {
        int tq = qb * 128 + w * 32 + m * 16 + l4 * 4 + j;
        int col = h * HDIM + n * 16 + lm;
        float v = oacc[m][n][j] / lrow[m][j];
        ob[(size_t)(b * NT + tq) * ND + col] = f2b(v);
      }
}

// ---------------------------------------------------------------- layernorm
__global__ void k_ln(const float* __restrict__ xf, const float* __restrict__ g,
                     const float* __restrict__ bta, u16* __restrict__ xb) {
  __shared__ float red[4];
  int row = blockIdx.x, tid = threadIdx.x;
  int w = tid >> 6;
  int c = tid * 4;
  float4 x = *(const float4*)(xf + (size_t)row * ND + c);
  float s = x.x + x.y + x.z + x.w;
#pragma unroll
  for (int off = 1; off < 64; off <<= 1) s += __shfl_xor(s, off, 64);
  if ((tid & 63) == 0) red[w] = s;
  __syncthreads();
  float mu = (red[0] + red[1] + red[2] + red[3]) * (1.0f / ND);
  float d0 = x.x - mu, d1 = x.y - mu, d2 = x.z - mu, d3 = x.w - mu;
  float v = d0 * d0 + d1 * d1 + d2 * d2 + d3 * d3;
  __syncthreads();
#pragma unroll
  for (int off = 1; off < 64; off <<= 1) v += __shfl_xor(v, off, 64);
  if ((tid & 63) == 0) red[w] = v;
  __syncthreads();
  float var = (red[0] + red[1] + red[2] + red[3]) * (1.0f / ND);
  float rs = rsqrtf(var + 1e-5f);
  float4 gg = *(const float4*)(g + c);
  float4 bb = *(const float4*)(bta + c);
  u16* o = xb + (size_t)row * ND + c;
  o[0] = f2b(d0 * rs * gg.x + bb.x);
  o[1] = f2b(d1 * rs * gg.y + bb.y);
  o[2] = f2b(d2 * rs * gg.z + bb.z);
  o[3] = f2b(d3 * rs * gg.w + bb.w);
}

// ---------------------------------------------------------------- loss
__global__ void k_loss_row(const float* __restrict__ logits, const int* __restrict__ tgt,
                           float* __restrict__ lossbuf) {
  __shared__ float ms[4], ss[4];
  int row = blockIdx.x, tid = threadIdx.x;
  const float* lr = logits + (size_t)row * NV;
  float m = -1e30f, s = 0.f;
  for (int i = tid; i < NV; i += 256) {
    float x = lr[i];
    float nm = fmaxf(m, x);
    s = s * exp2f((m - nm) * L2E) + exp2f((x - nm) * L2E);
    m = nm;
  }
#pragma unroll
  for (int off = 1; off < 64; off <<= 1) {
    float mo = __shfl_xor(m, off, 64);
    float so = __shfl_xor(s, off, 64);
    float nm = fmaxf(m, mo);
    s = s * exp2f((m - nm) * L2E) + so * exp2f((mo - nm) * L2E);
    m = nm;
  }
  if ((tid & 63) == 0) { ms[tid >> 6] = m; ss[tid >> 6] = s; }
  __syncthreads();
  if (tid == 0) {
    float M = fmaxf(fmaxf(ms[0], ms[1]), fmaxf(ms[2], ms[3]));
    float S = ss[0] * exp2f((ms[0] - M) * L2E) + ss[1] * exp2f((ms[1] - M) * L2E) +
              ss[2] * exp2f((ms[2] - M) * L2E) + ss[3] * exp2f((ms[3] - M) * L2E);
    float lse = M + logf(S);
    lossbuf[row] = lse - lr[tgt[row]];
  }
}

__global__ void k_loss_final(const float* __restrict__ lossbuf, float* __restrict__ out) {
  __shared__ float red[4];
  int tid = threadIdx.x;
  float s = 0.f;
  for (int i = tid; i < BT; i += 256) s += lossbuf[i];
#pragma unroll
  for (int off = 1; off < 64; off <<= 1) s += __shfl_xor(s, off, 64);
  if ((tid & 63) == 0) red[tid >> 6] = s;
  __syncthreads();
  if (tid == 0) out[0] = (red[0] + red[1] + red[2] + red[3]) * (1.0f / BT);
}

// ---------------------------------------------------------------- launch
extern "C" void kernel_launch(void* const* d_in, const int* in_sizes, int n_in,
                              void* d_out, int out_size, void* d_ws, size_t ws_size,
                              hipStream_t stream) {
  const int* idx = (const int*)d_in[0];
  const int* tgt = (const int*)d_in[1];
  const float* tok = (const float*)d_in[2];
  const float* pos = (const float*)d_in[3];
  const float* Wq = (const float*)d_in[4];
  const float* Wk = (const float*)d_in[5];
  const float* Wv = (const float*)d_in[6];
  const float* Wo = (const float*)d_in[7];
  const float* bo = (const float*)d_in[8];
  const float* W1 = (const float*)d_in[9];
  const float* b1 = (const float*)d_in[10];
  const float* W2 = (const float*)d_in[11];
  const float* b2 = (const float*)d_in[12];
  const float* lng = (const float*)d_in[13];
  const float* lnb = (const float*)d_in[14];
  const float* Wf = (const float*)d_in[15];
  const float* bfp = (const float*)d_in[16];
  float* logits = (float*)d_out;
  float* lossp = logits + (size_t)BT * NV;

  char* ws = (char*)d_ws;
  u16* wT = (u16*)ws;                                   // 65,536,000 B (max: Wf^T)
  size_t off = 65536000;
  float* xf = (float*)(ws + off); off += (size_t)BT * ND * 4;
  u16* xb = (u16*)(ws + off);     off += (size_t)BT * ND * 2;
  u16* qkv = (u16*)(ws + off);    off += (size_t)BT * 3 * ND * 2;
  u16* obuf = (u16*)(ws + off);   off += (size_t)BT * ND * 2;
  u16* hb = (u16*)(ws + off);     off += (size_t)BT * ND4 * 2;
  float* lossbuf = (float*)(ws + off);

  u16* wqkvT = wT;                       // [3D][D]
  u16* woT = wT + (size_t)3 * ND * ND;   // [D][D]
  u16* w1T = woT + (size_t)ND * ND;      // [4D][D]
  u16* w2T = w1T + (size_t)ND4 * ND;     // [D][4D]

  k_embed<<<BT, 256, 0, stream>>>(idx, tok, pos, xf, xb);
  for (int l = 0; l < NL; ++l) {
    k_transpose_qkv<<<dim3(16, 48), 256, 0, stream>>>(Wq, Wk, Wv, wqkvT, l);
    k_transpose<<<dim3(16, 16), 256, 0, stream>>>(Wo + (size_t)l * ND * ND, woT, ND, ND);
    k_transpose<<<dim3(64, 16), 256, 0, stream>>>(W1 + (size_t)l * ND * ND4, w1T, ND, ND4);
    k_transpose<<<dim3(16, 64), 256, 0, stream>>>(W2 + (size_t)l * ND4 * ND, w2T, ND4, ND);
    k_gemm<0><<<dim3(24, 16), 256, 0, stream>>>(xb, wqkvT, nullptr, nullptr, qkv, ND, 3 * ND);
    k_attn<<<256, 256, 0, stream>>>(qkv, obuf);
    k_gemm<3><<<dim3(8, 16), 256, 0, stream>>>(obuf, woT, bo + (size_t)l * ND, xf, xb, ND, ND);
    k_gemm<2><<<dim3(32, 16), 256, 0, stream>>>(xb, w1T, b1 + (size_t)l * ND4, nullptr, hb, ND, ND4);
    k_gemm<3><<<dim3(8, 16), 256, 0, stream>>>(hb, w2T, b2 + (size_t)l * ND, xf, xb, ND4, ND);
  }
  k_transpose<<<dim3(500, 16), 256, 0, stream>>>(Wf, wT, ND, NV);
  k_ln<<<BT, 256, 0, stream>>>(xf, lng, lnb, xb);
  k_gemm<1><<<dim3(250, 16), 256, 0, stream>>>(xb, wT, bfp, logits, nullptr, ND, NV);
  k_loss_row<<<BT, 256, 0, stream>>>(logits, tgt, lossbuf);
  k_loss_final<<<1, 256, 0, stream>>>(lossbuf, lossp);
}